// Round 8
// baseline (213.775 us; speedup 1.0000x reference)
//
#include <hip/hip_runtime.h>
#include <math.h>

// DeepseekV3 TopK router, MI355X — R8 = R7 with the register-starvation fix:
// __launch_bounds__(512) WITHOUT the min-waves-per-EU arg (R5-R7 all pinned
// VGPR_Count=32, forcing AGPR shuffling / remat that inflated VALU work).
// Phase A: 8 lanes/token, u64 packed keys (monotone float bits | 255-idx),
// Batcher sort-8 + top-8 merges. One barrier. Phase B: wave 0, 1 thread/token.
// Numerics frozen: expf + IEEE 1/(1+e) divide (passed 4 rounds).

constexpr int N_EXPERTS  = 256;
constexpr int N_GROUP    = 8;
constexpr int EG         = 32;
constexpr int TOPK_GROUP = 4;
constexpr int TOP_K      = 8;
constexpr int BLOCK      = 512;              // 64 tokens per block
constexpr int TPB_TOK    = BLOCK / N_GROUP;  // 64

typedef unsigned int u32;
typedef unsigned long long u64;

// monotone map: a<b (float) <=> M(a)<M(b) (u32)
__device__ __forceinline__ u32 fmono(float f) {
  const u32 u = __float_as_uint(f);
  return u ^ ((u32)((int)u >> 31) | 0x80000000u);
}
__device__ __forceinline__ float fmono_inv(u32 m) {
  const u32 u = (m & 0x80000000u) ? (m ^ 0x80000000u) : ~m;
  return __uint_as_float(u);
}
// key: larger = (bigger value, then smaller index)
__device__ __forceinline__ u64 mkkey(float v, int idx) {
  return ((u64)fmono(v) << 32) | (u32)(255 - idx);
}
__device__ __forceinline__ int key_idx(u64 k) { return 255 - (int)(k & 0xFFu); }
__device__ __forceinline__ float key_val(u64 k) { return fmono_inv((u32)(k >> 32)); }

// descending compare-swap: larger key to a
__device__ __forceinline__ void kswap(u64& a, u64& b) {
  const bool sw = b > a;
  const u64 t = sw ? b : a;
  b = sw ? a : b;
  a = t;
}

// Batcher odd-even mergesort network for 8 (19 comparators), descending.
__device__ __forceinline__ void sort8(u64 (&k)[8]) {
  kswap(k[0], k[1]); kswap(k[2], k[3]); kswap(k[4], k[5]); kswap(k[6], k[7]);
  kswap(k[0], k[2]); kswap(k[1], k[3]); kswap(k[4], k[6]); kswap(k[5], k[7]);
  kswap(k[1], k[2]); kswap(k[5], k[6]);
  kswap(k[0], k[4]); kswap(k[1], k[5]); kswap(k[2], k[6]); kswap(k[3], k[7]);
  kswap(k[2], k[4]); kswap(k[3], k[5]);
  kswap(k[1], k[2]); kswap(k[3], k[4]); kswap(k[5], k[6]);
}

// A = top-8 of (A, B); both descending sorted. Keys are unique -> exact.
__device__ __forceinline__ void merge8(u64 (&A)[8], const u64 (&B)[8]) {
  u64 R[8];
#pragma unroll
  for (int i = 0; i < 8; ++i) {
    const bool a = A[i] >= B[7 - i];
    R[i] = a ? A[i] : B[7 - i];
  }
  kswap(R[0], R[4]); kswap(R[1], R[5]); kswap(R[2], R[6]); kswap(R[3], R[7]);
  kswap(R[0], R[2]); kswap(R[1], R[3]); kswap(R[4], R[6]); kswap(R[5], R[7]);
  kswap(R[0], R[1]); kswap(R[2], R[3]); kswap(R[4], R[5]); kswap(R[6], R[7]);
#pragma unroll
  for (int i = 0; i < 8; ++i) A[i] = R[i];
}

__global__ __launch_bounds__(BLOCK) void deepseek_topk_router_r8(
    const float* __restrict__ logits,
    const float* __restrict__ bias,
    float* __restrict__ out,   // [T*8] indices (as float) then [T*8] weights
    int T) {
  __shared__ __align__(16) float gsb[BLOCK];          // 2 KB group scores
  __shared__ u64 kbuf[N_GROUP][BLOCK];                // 32 KB sorted lists

  const int tid = threadIdx.x;
  const int id  = blockIdx.x * BLOCK + tid;
  const int t   = id >> 3;              // token (T*8 % 512 == 0, grid exact)
  const int q   = id & 7;               // group handled by this lane

  const float4* row4 =
      reinterpret_cast<const float4*>(logits + (size_t)t * N_EXPERTS + q * EG);
  const float4* b4 = reinterpret_cast<const float4*>(bias + q * EG);

  // all 8 row loads in flight before any dependent math
  float4 x[8];
#pragma unroll
  for (int u = 0; u < 8; ++u) x[u] = row4[u];
  float4 bb[8];
#pragma unroll
  for (int u = 0; u < 8; ++u) bb[u] = b4[u];

  // ---- Phase A: sorted top-8 keys of my group's 32 corrected scores ----
  u64 K[8];
#pragma unroll
  for (int c = 0; c < 4; ++c) {
    u64 C[8];
    const float xs[8] = {x[2*c].x, x[2*c].y, x[2*c].z, x[2*c].w,
                         x[2*c+1].x, x[2*c+1].y, x[2*c+1].z, x[2*c+1].w};
    const float bs[8] = {bb[2*c].x, bb[2*c].y, bb[2*c].z, bb[2*c].w,
                         bb[2*c+1].x, bb[2*c+1].y, bb[2*c+1].z, bb[2*c+1].w};
#pragma unroll
    for (int j = 0; j < 8; ++j) {
      const float e = expf(-xs[j]);                 // frozen numerics
      const float s = 1.0f / (1.0f + e);            // IEEE divide
      C[j] = mkkey(s + bs[j], q * EG + c * 8 + j);
    }
    sort8(C);
    if (c == 0) {
#pragma unroll
      for (int j = 0; j < 8; ++j) K[j] = C[j];
    } else {
      merge8(K, C);
    }
  }

  // ---- Publish group score + sorted list; single barrier ----
  gsb[tid] = key_val(K[0]) + key_val(K[1]);
#pragma unroll
  for (int k = 0; k < 8; ++k) kbuf[k][tid] = K[k];
  __syncthreads();
  if (tid >= TPB_TOK) return;           // waves 1..7 done

  // ---- Phase B: wave 0, one thread per token ----
  const int j   = tid;                  // local token
  const int tok = blockIdx.x * TPB_TOK + j;

  // 8 group scores (contiguous in gsb)
  const float4* gp = reinterpret_cast<const float4*>(&gsb[8 * j]);
  const float4 ga = gp[0], gb = gp[1];
  const float g[N_GROUP] = {ga.x, ga.y, ga.z, ga.w, gb.x, gb.y, gb.z, gb.w};

  // top-4 groups (ties -> lower index), collected in ascending group order
  int s0 = 0, s1 = 0, s2 = 0, s3 = 0, cnt = 0;
#pragma unroll
  for (int h = 0; h < N_GROUP; ++h) {
    int rank = 0;
#pragma unroll
    for (int m = 0; m < N_GROUP; ++m)
      rank += (m < h) ? (g[m] >= g[h] ? 1 : 0) : (g[m] > g[h] ? 1 : 0);
    const bool pick = (rank < TOPK_GROUP);
    s0 = (pick && cnt == 0) ? h : s0;
    s1 = (pick && cnt == 1) ? h : s1;
    s2 = (pick && cnt == 2) ? h : s2;
    s3 = (pick && cnt == 3) ? h : s3;
    cnt += pick ? 1 : 0;
  }

  // merge the 4 selected lists (key order is exact; any merge order OK)
  u64 A[8], B[8];
  const int base = 8 * j;
#pragma unroll
  for (int k = 0; k < 8; ++k) A[k] = kbuf[k][base + s0];
#pragma unroll
  for (int k = 0; k < 8; ++k) B[k] = kbuf[k][base + s1];
  merge8(A, B);
#pragma unroll
  for (int k = 0; k < 8; ++k) B[k] = kbuf[k][base + s2];
  merge8(A, B);
#pragma unroll
  for (int k = 0; k < 8; ++k) B[k] = kbuf[k][base + s3];
  merge8(A, B);

  // ---- Epilogue: weights = (c - bias[idx]) / sum * 2.5 ----
  float fi[8], sv[8];
  float sum = 0.0f;
#pragma unroll
  for (int k = 0; k < TOP_K; ++k) {
    const int idx = key_idx(A[k]);
    const float c = key_val(A[k]);
    sv[k] = c - bias[idx];              // recover sigmoid score (bias L1-hot)
    fi[k] = (float)idx;
    sum += sv[k];
  }
  const float scale = 2.5f / (sum + 1e-20f);

  float4* oi = reinterpret_cast<float4*>(out) + (size_t)tok * 2;
  oi[0] = make_float4(fi[0], fi[1], fi[2], fi[3]);
  oi[1] = make_float4(fi[4], fi[5], fi[6], fi[7]);
  float4* ow = reinterpret_cast<float4*>(out + (size_t)T * TOP_K) + (size_t)tok * 2;
  ow[0] = make_float4(sv[0] * scale, sv[1] * scale, sv[2] * scale, sv[3] * scale);
  ow[1] = make_float4(sv[4] * scale, sv[5] * scale, sv[6] * scale, sv[7] * scale);
}

extern "C" void kernel_launch(void* const* d_in, const int* in_sizes, int n_in,
                              void* d_out, int out_size, void* d_ws, size_t ws_size,
                              hipStream_t stream) {
  const float* logits = (const float*)d_in[0];
  const float* bias   = (const float*)d_in[1];
  float* out = (float*)d_out;
  const int T = in_sizes[0] / N_EXPERTS;           // 131072 (multiple of 64)
  const int blocks = T / TPB_TOK;                   // 2048
  deepseek_topk_router_r8<<<blocks, BLOCK, 0, stream>>>(logits, bias, out, T);
}

// Round 9
// 208.150 us; speedup vs baseline: 1.0270x; 1.0270x over previous
//
#include <hip/hip_runtime.h>
#include <math.h>

// DeepseekV3 TopK router, MI355X — R9 = R8 with the IEEE-divide bottleneck
// removed: sigmoid reciprocal computed as v_rcp_f32 + 2 Newton-Raphson FMA
// steps (VCC-free, ~1 ulp, d in (1,2)) instead of the div_scale/div_fmas/
// div_fixup sequence that serializes on VCC. Everything else frozen:
// u64 packed keys, Batcher sort-8 + top-8 merges, one barrier, wave-0 phase B.

constexpr int N_EXPERTS  = 256;
constexpr int N_GROUP    = 8;
constexpr int EG         = 32;
constexpr int TOPK_GROUP = 4;
constexpr int TOP_K      = 8;
constexpr int BLOCK      = 512;              // 64 tokens per block
constexpr int TPB_TOK    = BLOCK / N_GROUP;  // 64

typedef unsigned int u32;
typedef unsigned long long u64;

// monotone map: a<b (float) <=> M(a)<M(b) (u32)
__device__ __forceinline__ u32 fmono(float f) {
  const u32 u = __float_as_uint(f);
  return u ^ ((u32)((int)u >> 31) | 0x80000000u);
}
__device__ __forceinline__ float fmono_inv(u32 m) {
  const u32 u = (m & 0x80000000u) ? (m ^ 0x80000000u) : ~m;
  return __uint_as_float(u);
}
// key: larger = (bigger value, then smaller index)
__device__ __forceinline__ u64 mkkey(float v, int idx) {
  return ((u64)fmono(v) << 32) | (u32)(255 - idx);
}
__device__ __forceinline__ int key_idx(u64 k) { return 255 - (int)(k & 0xFFu); }
__device__ __forceinline__ float key_val(u64 k) { return fmono_inv((u32)(k >> 32)); }

// reciprocal of d in (1,2): v_rcp_f32 + 2 NR refinements. VCC-free, <=1 ulp.
__device__ __forceinline__ float recip_nr(float d) {
  float r = __builtin_amdgcn_rcpf(d);
  r = __builtin_fmaf(__builtin_fmaf(-d, r, 1.0f), r, r);
  r = __builtin_fmaf(__builtin_fmaf(-d, r, 1.0f), r, r);
  return r;
}

// descending compare-swap: larger key to a
__device__ __forceinline__ void kswap(u64& a, u64& b) {
  const bool sw = b > a;
  const u64 t = sw ? b : a;
  b = sw ? a : b;
  a = t;
}

// Batcher odd-even mergesort network for 8 (19 comparators), descending.
__device__ __forceinline__ void sort8(u64 (&k)[8]) {
  kswap(k[0], k[1]); kswap(k[2], k[3]); kswap(k[4], k[5]); kswap(k[6], k[7]);
  kswap(k[0], k[2]); kswap(k[1], k[3]); kswap(k[4], k[6]); kswap(k[5], k[7]);
  kswap(k[1], k[2]); kswap(k[5], k[6]);
  kswap(k[0], k[4]); kswap(k[1], k[5]); kswap(k[2], k[6]); kswap(k[3], k[7]);
  kswap(k[2], k[4]); kswap(k[3], k[5]);
  kswap(k[1], k[2]); kswap(k[3], k[4]); kswap(k[5], k[6]);
}

// A = top-8 of (A, B); both descending sorted. Keys are unique -> exact.
__device__ __forceinline__ void merge8(u64 (&A)[8], const u64 (&B)[8]) {
  u64 R[8];
#pragma unroll
  for (int i = 0; i < 8; ++i) {
    const bool a = A[i] >= B[7 - i];
    R[i] = a ? A[i] : B[7 - i];
  }
  kswap(R[0], R[4]); kswap(R[1], R[5]); kswap(R[2], R[6]); kswap(R[3], R[7]);
  kswap(R[0], R[2]); kswap(R[1], R[3]); kswap(R[4], R[6]); kswap(R[5], R[7]);
  kswap(R[0], R[1]); kswap(R[2], R[3]); kswap(R[4], R[5]); kswap(R[6], R[7]);
#pragma unroll
  for (int i = 0; i < 8; ++i) A[i] = R[i];
}

__global__ __launch_bounds__(BLOCK) void deepseek_topk_router_r9(
    const float* __restrict__ logits,
    const float* __restrict__ bias,
    float* __restrict__ out,   // [T*8] indices (as float) then [T*8] weights
    int T) {
  __shared__ __align__(16) float gsb[BLOCK];          // 2 KB group scores
  __shared__ u64 kbuf[N_GROUP][BLOCK];                // 32 KB sorted lists

  const int tid = threadIdx.x;
  const int id  = blockIdx.x * BLOCK + tid;
  const int t   = id >> 3;              // token (T*8 % 512 == 0, grid exact)
  const int q   = id & 7;               // group handled by this lane

  const float4* row4 =
      reinterpret_cast<const float4*>(logits + (size_t)t * N_EXPERTS + q * EG);
  const float4* b4 = reinterpret_cast<const float4*>(bias + q * EG);

  // all 8 row loads in flight before any dependent math
  float4 x[8];
#pragma unroll
  for (int u = 0; u < 8; ++u) x[u] = row4[u];
  float4 bb[8];
#pragma unroll
  for (int u = 0; u < 8; ++u) bb[u] = b4[u];

  // ---- Phase A: sorted top-8 keys of my group's 32 corrected scores ----
  u64 K[8];
#pragma unroll
  for (int c = 0; c < 4; ++c) {
    u64 C[8];
    const float xs[8] = {x[2*c].x, x[2*c].y, x[2*c].z, x[2*c].w,
                         x[2*c+1].x, x[2*c+1].y, x[2*c+1].z, x[2*c+1].w};
    const float bs[8] = {bb[2*c].x, bb[2*c].y, bb[2*c].z, bb[2*c].w,
                         bb[2*c+1].x, bb[2*c+1].y, bb[2*c+1].z, bb[2*c+1].w};
#pragma unroll
    for (int j = 0; j < 8; ++j) {
      const float e = expf(-xs[j]);                 // frozen: precise expf
      const float s = recip_nr(1.0f + e);           // 1/(1+e), VCC-free NR
      C[j] = mkkey(s + bs[j], q * EG + c * 8 + j);
    }
    sort8(C);
    if (c == 0) {
#pragma unroll
      for (int j = 0; j < 8; ++j) K[j] = C[j];
    } else {
      merge8(K, C);
    }
  }

  // ---- Publish group score + sorted list; single barrier ----
  gsb[tid] = key_val(K[0]) + key_val(K[1]);
#pragma unroll
  for (int k = 0; k < 8; ++k) kbuf[k][tid] = K[k];
  __syncthreads();
  if (tid >= TPB_TOK) return;           // waves 1..7 done

  // ---- Phase B: wave 0, one thread per token ----
  const int j   = tid;                  // local token
  const int tok = blockIdx.x * TPB_TOK + j;

  // 8 group scores (contiguous in gsb)
  const float4* gp = reinterpret_cast<const float4*>(&gsb[8 * j]);
  const float4 ga = gp[0], gb = gp[1];
  const float g[N_GROUP] = {ga.x, ga.y, ga.z, ga.w, gb.x, gb.y, gb.z, gb.w};

  // top-4 groups (ties -> lower index), collected in ascending group order
  int s0 = 0, s1 = 0, s2 = 0, s3 = 0, cnt = 0;
#pragma unroll
  for (int h = 0; h < N_GROUP; ++h) {
    int rank = 0;
#pragma unroll
    for (int m = 0; m < N_GROUP; ++m)
      rank += (m < h) ? (g[m] >= g[h] ? 1 : 0) : (g[m] > g[h] ? 1 : 0);
    const bool pick = (rank < TOPK_GROUP);
    s0 = (pick && cnt == 0) ? h : s0;
    s1 = (pick && cnt == 1) ? h : s1;
    s2 = (pick && cnt == 2) ? h : s2;
    s3 = (pick && cnt == 3) ? h : s3;
    cnt += pick ? 1 : 0;
  }

  // merge the 4 selected lists (key order is exact; any merge order OK)
  u64 A[8], B[8];
  const int base = 8 * j;
#pragma unroll
  for (int k = 0; k < 8; ++k) A[k] = kbuf[k][base + s0];
#pragma unroll
  for (int k = 0; k < 8; ++k) B[k] = kbuf[k][base + s1];
  merge8(A, B);
#pragma unroll
  for (int k = 0; k < 8; ++k) B[k] = kbuf[k][base + s2];
  merge8(A, B);
#pragma unroll
  for (int k = 0; k < 8; ++k) B[k] = kbuf[k][base + s3];
  merge8(A, B);

  // ---- Epilogue: weights = (c - bias[idx]) / sum * 2.5 ----
  float fi[8], sv[8];
  float sum = 0.0f;
#pragma unroll
  for (int k = 0; k < TOP_K; ++k) {
    const int idx = key_idx(A[k]);
    const float c = key_val(A[k]);
    sv[k] = c - bias[idx];              // recover sigmoid score (bias L1-hot)
    fi[k] = (float)idx;
    sum += sv[k];
  }
  const float scale = 2.5f / (sum + 1e-20f);  // once per token: IEEE is fine

  float4* oi = reinterpret_cast<float4*>(out) + (size_t)tok * 2;
  oi[0] = make_float4(fi[0], fi[1], fi[2], fi[3]);
  oi[1] = make_float4(fi[4], fi[5], fi[6], fi[7]);
  float4* ow = reinterpret_cast<float4*>(out + (size_t)T * TOP_K) + (size_t)tok * 2;
  ow[0] = make_float4(sv[0] * scale, sv[1] * scale, sv[2] * scale, sv[3] * scale);
  ow[1] = make_float4(sv[4] * scale, sv[5] * scale, sv[6] * scale, sv[7] * scale);
}

extern "C" void kernel_launch(void* const* d_in, const int* in_sizes, int n_in,
                              void* d_out, int out_size, void* d_ws, size_t ws_size,
                              hipStream_t stream) {
  const float* logits = (const float*)d_in[0];
  const float* bias   = (const float*)d_in[1];
  float* out = (float*)d_out;
  const int T = in_sizes[0] / N_EXPERTS;           // 131072 (multiple of 64)
  const int blocks = T / TPB_TOK;                   // 2048
  deepseek_topk_router_r9<<<blocks, BLOCK, 0, stream>>>(logits, bias, out, T);
}